// Round 2
// baseline (227.146 us; speedup 1.0000x reference)
//
#include <hip/hip_runtime.h>
#include <hip/hip_fp16.h>

// LMKAN_2D: out(O=256,B=4096) = relu(W(256x128)@x(128x4096) + bias_l)
//           + w_lm * sum_p bilinear4(fp[i,j,:,p])
// K1: transpose fp (4225 panels)[o=256][p=64] f32 -> fpt [panel][p=64][o=256] f16
//     (coalesced o-gather, table 132 MiB -> L3-resident).
// K2: block(256 thr, 4 waves) per b-column. Waves split p 4x16 (shorter dep
//     chain, 32 waves/CU). Within a wave, lane-halves own rows i / i+1 and
//     each lane loads the (j, j+1) panel pair as 16B uint4 (8 o's) -> half the
//     load instructions of the 8B scheme. __shfl_xor(32) merges halves, LDS
//     merges waves, fused linear epilogue (1 o per thread, 128 FMAs).

#define NB 4096
#define ND 128
#define NO 256
#define NP 64
#define NG 65
#define PANEL 16384  // 256*64 elements per (i,j) panel

__device__ __forceinline__ int bsearch65(const float* B, float v) {
  int lo = 0, hi = 65;
  while (lo < hi) {
    int m = (lo + hi) >> 1;
    if (B[m] <= v) lo = m + 1; else hi = m;
  }
  int i = lo - 1;
  return i < 0 ? 0 : (i > 63 ? 63 : i);
}

__global__ __launch_bounds__(128) void lmkan_transpose(
    const float* __restrict__ src, __half* __restrict__ dst) {
  const int panel = blockIdx.x;
  const int t = threadIdx.x;            // 0..127, handles o0=2t, 2t+1
  const float* s = src + (size_t)panel * PANEL;
  __half* d = dst + (size_t)panel * PANEL;
  const int o0 = 2 * t;
  const float4* ra = reinterpret_cast<const float4*>(s + (size_t)o0 * 64);
  const float4* rb = reinterpret_cast<const float4*>(s + (size_t)(o0 + 1) * 64);
#pragma unroll 4
  for (int pc = 0; pc < 16; ++pc) {
    float4 a = ra[pc];   // row o0,   p = 4pc..4pc+3
    float4 b = rb[pc];   // row o0+1
    *reinterpret_cast<__half2*>(d + (size_t)(4 * pc + 0) * NO + o0) = __floats2half2_rn(a.x, b.x);
    *reinterpret_cast<__half2*>(d + (size_t)(4 * pc + 1) * NO + o0) = __floats2half2_rn(a.y, b.y);
    *reinterpret_cast<__half2*>(d + (size_t)(4 * pc + 2) * NO + o0) = __floats2half2_rn(a.z, b.z);
    *reinterpret_cast<__half2*>(d + (size_t)(4 * pc + 3) * NO + o0) = __floats2half2_rn(a.w, b.w);
  }
}

__device__ __forceinline__ void fma8(float acc[8], float w, uint4 v) {
  const __half2* h = reinterpret_cast<const __half2*>(&v);
#pragma unroll
  for (int k = 0; k < 4; ++k) {
    float2 f = __half22float2(h[k]);
    acc[2 * k]     = fmaf(w, f.x, acc[2 * k]);
    acc[2 * k + 1] = fmaf(w, f.y, acc[2 * k + 1]);
  }
}

__global__ __launch_bounds__(256) void lmkan_gather4(
    const float* __restrict__ x, const float* __restrict__ scale,
    const float* __restrict__ biasp, const float* __restrict__ W,
    const float* __restrict__ bias_l, const float* __restrict__ wlm_p,
    const int* __restrict__ relu_p, const __half* __restrict__ fpt,
    float* __restrict__ out) {
  const int b = blockIdx.x;
  const int t = threadIdx.x;   // 0..255
  const int w = t >> 6;        // wave 0..3 -> p in [16w, 16w+16)
  const int l = t & 63;
  const int h = l >> 5;        // 0: row i, 1: row i+1
  const int L = l & 31;        // o block: [8L, 8L+8)

  __shared__ float borders[66];
  __shared__ __align__(16) float xcol[ND];
  __shared__ int pbase[NP];
  __shared__ float4 pw[NP];
  __shared__ float lm[4][NO];

  if (t < 65) {
    float pk = fminf(fmaxf((float)t * (1.0f / 64.0f), 0.0078125f), 0.9921875f);
    borders[t] = 1.41421356237309515f * erfinvf(2.0f * pk - 1.0f);
  }
  if (t < ND) xcol[t] = x[(size_t)t * NB + b];
  __syncthreads();

  if (t < NP) {
    const int p = t;
    float x1 = xcol[2 * p]     * scale[2 * p]     + biasp[2 * p];
    float x2 = xcol[2 * p + 1] * scale[2 * p + 1] + biasp[2 * p + 1];
    const float lo = borders[0];
    const float hi = borders[64] - 1e-6f;
    x1 = fminf(fmaxf(x1, lo), hi);
    x2 = fminf(fmaxf(x2, lo), hi);
    int i = bsearch65(borders, x1);
    int j = bsearch65(borders, x2);
    float t1 = (x1 - borders[i]) / (borders[i + 1] - borders[i]);
    float t2 = (x2 - borders[j]) / (borders[j + 1] - borders[j]);
    pbase[p] = i * NG + j;
    pw[p] = make_float4((1.0f - t1) * (1.0f - t2),  // (i,   j)
                        t1 * (1.0f - t2),           // (i+1, j)
                        (1.0f - t1) * t2,           // (i,   j+1)
                        t1 * t2);                   // (i+1, j+1)
  }
  __syncthreads();

  float acc[8] = {0, 0, 0, 0, 0, 0, 0, 0};
  const int p0 = w * 16;
#pragma unroll 8
  for (int pi = 0; pi < 16; ++pi) {
    const int p = p0 + pi;
    const int base = pbase[p] + h * NG;   // row i or i+1
    const float4 wv = pw[p];
    const float wA = h ? wv.y : wv.x;     // (row, j)
    const float wB = h ? wv.w : wv.z;     // (row, j+1)
    const __half* q = fpt + ((size_t)base * NP + p) * NO + 8 * L;
    uint4 v0 = *reinterpret_cast<const uint4*>(q);
    uint4 v1 = *reinterpret_cast<const uint4*>(q + PANEL);  // j+1 panel
    fma8(acc, wA, v0);
    fma8(acc, wB, v1);
  }
  // merge the two lane-halves (rows i and i+1)
#pragma unroll
  for (int k = 0; k < 8; ++k) acc[k] += __shfl_xor(acc[k], 32, 64);
  if (l < 32) {
#pragma unroll
    for (int k = 0; k < 8; ++k) lm[w][8 * L + k] = acc[k];
  }
  __syncthreads();

  // epilogue: thread t <-> output row o = t
  const int o = t;
  float lmsum = lm[0][o] + lm[1][o] + lm[2][o] + lm[3][o];
  const float4* wr = reinterpret_cast<const float4*>(W + (size_t)o * ND);
  const float4* xc4 = reinterpret_cast<const float4*>(xcol);
  float s = 0.0f;
#pragma unroll 8
  for (int d4 = 0; d4 < ND / 4; ++d4) {
    float4 wv = wr[d4];
    float4 xv = xc4[d4];
    s = fmaf(wv.x, xv.x, s);
    s = fmaf(wv.y, xv.y, s);
    s = fmaf(wv.z, xv.z, s);
    s = fmaf(wv.w, xv.w, s);
  }
  s += bias_l[o];
  if (relu_p[0]) s = fmaxf(s, 0.0f);
  out[(size_t)o * NB + b] = s + wlm_p[0] * lmsum;
}

// Fallback: direct fp32 gather from original layout (exact, slow) if ws too small.
__global__ __launch_bounds__(64) void lmkan_gather_direct(
    const float* __restrict__ x, const float* __restrict__ scale,
    const float* __restrict__ biasp, const float* __restrict__ W,
    const float* __restrict__ bias_l, const float* __restrict__ wlm_p,
    const int* __restrict__ relu_p, const float* __restrict__ fp,
    float* __restrict__ out) {
  const int b = blockIdx.x;
  const int t = threadIdx.x;

  __shared__ float borders[66];
  __shared__ __align__(16) float xcol[ND];
  __shared__ int pbase[NP];
  __shared__ float4 pw[NP];

  for (int k = t; k < 65; k += 64) {
    float pk = fminf(fmaxf((float)k * (1.0f / 64.0f), 0.0078125f), 0.9921875f);
    borders[k] = 1.41421356237309515f * erfinvf(2.0f * pk - 1.0f);
  }
  xcol[t]      = x[(size_t)t * NB + b];
  xcol[t + 64] = x[(size_t)(t + 64) * NB + b];
  __syncthreads();

  {
    const int p = t;
    float x1 = xcol[2 * p]     * scale[2 * p]     + biasp[2 * p];
    float x2 = xcol[2 * p + 1] * scale[2 * p + 1] + biasp[2 * p + 1];
    const float lo = borders[0];
    const float hi = borders[64] - 1e-6f;
    x1 = fminf(fmaxf(x1, lo), hi);
    x2 = fminf(fmaxf(x2, lo), hi);
    int i = bsearch65(borders, x1);
    int j = bsearch65(borders, x2);
    float t1 = (x1 - borders[i]) / (borders[i + 1] - borders[i]);
    float t2 = (x2 - borders[j]) / (borders[j + 1] - borders[j]);
    pbase[p] = i * NG + j;
    pw[p] = make_float4((1.0f - t1) * (1.0f - t2), t1 * (1.0f - t2),
                        (1.0f - t1) * t2, t1 * t2);
  }
  __syncthreads();

  float acc[4] = {0, 0, 0, 0};
  for (int p = 0; p < NP; ++p) {
    int base = pbase[p];
    float4 wv = pw[p];
#pragma unroll
    for (int k = 0; k < 4; ++k) {
      size_t r = ((size_t)base * NO + (4 * t + k)) * NP + p;
      acc[k] += wv.x * fp[r] + wv.y * fp[r + 65 * PANEL] +
                wv.z * fp[r + PANEL] + wv.w * fp[r + 66 * PANEL];
    }
  }

  const float wlm = wlm_p[0];
  const int rl = relu_p[0];
  const float4* xc4 = reinterpret_cast<const float4*>(xcol);
#pragma unroll
  for (int k = 0; k < 4; ++k) {
    const int o = 4 * t + k;
    const float4* wr = reinterpret_cast<const float4*>(W + (size_t)o * ND);
    float s = 0.0f;
#pragma unroll 8
    for (int d4 = 0; d4 < ND / 4; ++d4) {
      float4 wv = wr[d4];
      float4 xv = xc4[d4];
      s = fmaf(wv.x, xv.x, s);
      s = fmaf(wv.y, xv.y, s);
      s = fmaf(wv.z, xv.z, s);
      s = fmaf(wv.w, xv.w, s);
    }
    s += bias_l[o];
    if (rl) s = fmaxf(s, 0.0f);
    out[(size_t)o * NB + b] = s + wlm * acc[k];
  }
}

extern "C" void kernel_launch(void* const* d_in, const int* in_sizes, int n_in,
                              void* d_out, int out_size, void* d_ws, size_t ws_size,
                              hipStream_t stream) {
  const float* x     = reinterpret_cast<const float*>(d_in[0]);
  const float* wlm   = reinterpret_cast<const float*>(d_in[1]);
  const int*   relu  = reinterpret_cast<const int*>(d_in[2]);
  const float* fp    = reinterpret_cast<const float*>(d_in[3]);
  const float* scale = reinterpret_cast<const float*>(d_in[4]);
  const float* biasp = reinterpret_cast<const float*>(d_in[5]);
  const float* W     = reinterpret_cast<const float*>(d_in[6]);
  const float* bl    = reinterpret_cast<const float*>(d_in[7]);
  float* out = reinterpret_cast<float*>(d_out);

  const size_t need = (size_t)NG * NG * PANEL * sizeof(__half);  // 132 MiB
  if (ws_size >= need) {
    __half* fpt = reinterpret_cast<__half*>(d_ws);
    lmkan_transpose<<<NG * NG, 128, 0, stream>>>(fp, fpt);
    lmkan_gather4<<<NB, 256, 0, stream>>>(x, scale, biasp, W, bl, wlm, relu, fpt, out);
  } else {
    lmkan_gather_direct<<<NB, 64, 0, stream>>>(x, scale, biasp, W, bl, wlm, relu, fp, out);
  }
}

// Round 3
// 195.105 us; speedup vs baseline: 1.1642x; 1.1642x over previous
//
#include <hip/hip_runtime.h>
#include <hip/hip_fp16.h>

// LMKAN_2D: out(O=256,B=4096) = relu(W(256x128)@x(128x4096) + bias_l)
//           + w_lm * sum_p bilinear4(fp[i,j,:,p])
// K1 transpose: fp[i][j][o][p] f32 -> fpt[i][p][j][o] f16 (132 MiB, L3-fit).
//    Layout puts (j, j+1) corner rows CONTIGUOUS -> gather reads 1KB segments.
//    Coalesced loads -> LDS (padded, conflict-free) -> 16B packed stores.
// K2 gather: block per b (256 thr = 4 waves x 16 p's). Per p: two contiguous
//    1KB wave reads (row i, row i+1), lane-halves own j / j+1. shfl merge,
//    LDS merge, out = wlm * lmkan only.
// K3 linear: separate 128-block GEMM (W re-read 16MB total instead of 512MB
//    inside gather), RMW-adds relu(Wx+b) into out with coalesced 128B runs.

#define NB 4096
#define ND 128
#define NO 256
#define NP 64
#define NG 65
#define PANEL 16384            // 256*64 elements per (i,j) panel
#define ROW2OFF (64 * 65 * 256)  // halves: (i,p,j,0) -> (i+1,p,j,0)

union Pack8 { __half h[8]; uint4 v; };

__device__ __forceinline__ int bsearch65(const float* B, float v) {
  int lo = 0, hi = 65;
  while (lo < hi) {
    int m = (lo + hi) >> 1;
    if (B[m] <= v) lo = m + 1; else hi = m;
  }
  int i = lo - 1;
  return i < 0 ? 0 : (i > 63 ? 63 : i);
}

// ---- K1: transpose fp -> fpt[i][p][j][o] fp16 ----
__global__ __launch_bounds__(256) void lmkan_transpose2(
    const float* __restrict__ src, __half* __restrict__ dst) {
  const int panel = blockIdx.x;       // = i*65 + j
  const int i = panel / NG, j = panel % NG;
  const int t = threadIdx.x;
  __shared__ __half lds[256 * 72];    // [o][64+8 pad]

  const float4* s4 = reinterpret_cast<const float4*>(src + (size_t)panel * PANEL);
#pragma unroll
  for (int k = 0; k < 16; ++k) {
    int idx4 = t + 256 * k;           // float4 index; 1KB contiguous per wave
    float4 v = s4[idx4];
    int o = idx4 >> 4;
    int p0 = (idx4 & 15) * 4;
    union { __half2 h2[2]; uint2 u; } pk;
    pk.h2[0] = __floats2half2_rn(v.x, v.y);
    pk.h2[1] = __floats2half2_rn(v.z, v.w);
    *reinterpret_cast<uint2*>(&lds[o * 72 + p0]) = pk.u;
  }
  __syncthreads();

  const int p = t & 63, oc = t >> 6;  // thread -> (p-row, o-chunk of 64)
  __half* dbase = dst + (((size_t)(i * 64 + p) * NG + j) * NO) + oc * 64;
#pragma unroll
  for (int s = 0; s < 8; ++s) {
    Pack8 pk;
#pragma unroll
    for (int r = 0; r < 8; ++r) pk.h[r] = lds[(oc * 64 + 8 * s + r) * 72 + p];
    *reinterpret_cast<uint4*>(dbase + 8 * s) = pk.v;
  }
}

__device__ __forceinline__ void fma8(float acc[8], float w, uint4 v) {
  const __half2* h = reinterpret_cast<const __half2*>(&v);
#pragma unroll
  for (int k = 0; k < 4; ++k) {
    float2 f = __half22float2(h[k]);
    acc[2 * k]     = fmaf(w, f.x, acc[2 * k]);
    acc[2 * k + 1] = fmaf(w, f.y, acc[2 * k + 1]);
  }
}

// ---- K2: gather, out = wlm * lmkan ----
__global__ __launch_bounds__(256) void lmkan_gather4(
    const float* __restrict__ x, const float* __restrict__ scale,
    const float* __restrict__ biasp, const float* __restrict__ wlm_p,
    const __half* __restrict__ fpt, float* __restrict__ out) {
  const int b = blockIdx.x;
  const int t = threadIdx.x;   // 0..255
  const int w = t >> 6;        // wave -> p in [16w, 16w+16)
  const int l = t & 63;
  const int sideJ = l >> 5;    // 0: corner j, 1: corner j+1
  const int o0 = 8 * (l & 31); // o block [o0, o0+8)

  __shared__ float borders[66];
  __shared__ float xcol[ND];
  __shared__ int pbaseEl[NP];  // half-index of (i, p, j, 0)
  __shared__ float4 pw[NP];
  __shared__ float lm[4][NO];

  if (t < 65) {
    float pk = fminf(fmaxf((float)t * (1.0f / 64.0f), 0.0078125f), 0.9921875f);
    borders[t] = 1.41421356237309515f * erfinvf(2.0f * pk - 1.0f);
  }
  if (t < ND) xcol[t] = x[(size_t)t * NB + b];
  __syncthreads();

  if (t < NP) {
    const int p = t;
    float x1 = xcol[2 * p]     * scale[2 * p]     + biasp[2 * p];
    float x2 = xcol[2 * p + 1] * scale[2 * p + 1] + biasp[2 * p + 1];
    const float lo = borders[0];
    const float hi = borders[64] - 1e-6f;
    x1 = fminf(fmaxf(x1, lo), hi);
    x2 = fminf(fmaxf(x2, lo), hi);
    int i = bsearch65(borders, x1);
    int j = bsearch65(borders, x2);
    float t1 = (x1 - borders[i]) / (borders[i + 1] - borders[i]);
    float t2 = (x2 - borders[j]) / (borders[j + 1] - borders[j]);
    pbaseEl[p] = ((i * 64 + p) * NG + j) * NO;
    pw[p] = make_float4((1.0f - t1) * (1.0f - t2),  // (i,   j)
                        t1 * (1.0f - t2),           // (i+1, j)
                        (1.0f - t1) * t2,           // (i,   j+1)
                        t1 * t2);                   // (i+1, j+1)
  }
  __syncthreads();

  float acc[8] = {0, 0, 0, 0, 0, 0, 0, 0};
  const int p0 = w * 16;
#pragma unroll 4
  for (int pi = 0; pi < 16; ++pi) {
    const int p = p0 + pi;
    const float4 wv = pw[p];
    const float wA = sideJ ? wv.z : wv.x;  // row i,   (j | j+1)
    const float wB = sideJ ? wv.w : wv.y;  // row i+1, (j | j+1)
    const __half* q = fpt + pbaseEl[p] + 8 * l;  // 1KB contiguous per wave
    uint4 v0 = *reinterpret_cast<const uint4*>(q);
    uint4 v1 = *reinterpret_cast<const uint4*>(q + ROW2OFF);
    fma8(acc, wA, v0);
    fma8(acc, wB, v1);
  }
  // merge j / j+1 lane-halves
#pragma unroll
  for (int k = 0; k < 8; ++k) acc[k] += __shfl_xor(acc[k], 32, 64);
  if (l < 32) {
#pragma unroll
    for (int k = 0; k < 8; ++k) lm[w][o0 + k] = acc[k];
  }
  __syncthreads();

  const int o = t;
  float lmsum = lm[0][o] + lm[1][o] + lm[2][o] + lm[3][o];
  out[(size_t)o * NB + b] = wlm_p[0] * lmsum;
}

// ---- K3: out += relu(W@x + bias) ----
__global__ __launch_bounds__(256) void lmkan_linear(
    const float* __restrict__ x, const float* __restrict__ W,
    const float* __restrict__ bias_l, const int* __restrict__ relu_p,
    float* __restrict__ out) {
  const int b0 = blockIdx.x * 32;
  const int t = threadIdx.x;          // = output row o
  __shared__ __align__(16) float xs[32 * 132];  // [bb][d], pad 132 (16B-aligned rows)

#pragma unroll
  for (int k = 0; k < 16; ++k) {
    int idx = t + 256 * k;            // idx = d*32 + bb -> coalesced in b
    int d = idx >> 5, bb = idx & 31;
    xs[bb * 132 + d] = x[(size_t)d * NB + b0 + bb];
  }
  __syncthreads();

  float acc[32];
#pragma unroll
  for (int bb = 0; bb < 32; ++bb) acc[bb] = 0.0f;

  const float4* W4 = reinterpret_cast<const float4*>(W + (size_t)t * ND);
#pragma unroll 8
  for (int d4 = 0; d4 < 32; ++d4) {
    float4 wv = W4[d4];
#pragma unroll
    for (int bb = 0; bb < 32; ++bb) {
      float4 xv = *reinterpret_cast<const float4*>(&xs[bb * 132 + d4 * 4]);
      acc[bb] = fmaf(wv.x, xv.x, acc[bb]);
      acc[bb] = fmaf(wv.y, xv.y, acc[bb]);
      acc[bb] = fmaf(wv.z, xv.z, acc[bb]);
      acc[bb] = fmaf(wv.w, xv.w, acc[bb]);
    }
  }

  const float bias = bias_l[t];
  const int rl = relu_p[0];
  float* orow = out + (size_t)t * NB + b0;
#pragma unroll
  for (int bb = 0; bb < 32; ++bb) {
    float v = acc[bb] + bias;
    if (rl) v = fmaxf(v, 0.0f);
    orow[bb] += v;   // RMW: gather already wrote wlm*lmkan
  }
}

// ---- Fallback: direct fp32 gather, fused linear (exact, slow) ----
__global__ __launch_bounds__(64) void lmkan_gather_direct(
    const float* __restrict__ x, const float* __restrict__ scale,
    const float* __restrict__ biasp, const float* __restrict__ W,
    const float* __restrict__ bias_l, const float* __restrict__ wlm_p,
    const int* __restrict__ relu_p, const float* __restrict__ fp,
    float* __restrict__ out) {
  const int b = blockIdx.x;
  const int t = threadIdx.x;

  __shared__ float borders[66];
  __shared__ __align__(16) float xcol[ND];
  __shared__ int pbase[NP];
  __shared__ float4 pw[NP];

  for (int k = t; k < 65; k += 64) {
    float pk = fminf(fmaxf((float)k * (1.0f / 64.0f), 0.0078125f), 0.9921875f);
    borders[k] = 1.41421356237309515f * erfinvf(2.0f * pk - 1.0f);
  }
  xcol[t]      = x[(size_t)t * NB + b];
  xcol[t + 64] = x[(size_t)(t + 64) * NB + b];
  __syncthreads();

  {
    const int p = t;
    float x1 = xcol[2 * p]     * scale[2 * p]     + biasp[2 * p];
    float x2 = xcol[2 * p + 1] * scale[2 * p + 1] + biasp[2 * p + 1];
    const float lo = borders[0];
    const float hi = borders[64] - 1e-6f;
    x1 = fminf(fmaxf(x1, lo), hi);
    x2 = fminf(fmaxf(x2, lo), hi);
    int i = bsearch65(borders, x1);
    int j = bsearch65(borders, x2);
    float t1 = (x1 - borders[i]) / (borders[i + 1] - borders[i]);
    float t2 = (x2 - borders[j]) / (borders[j + 1] - borders[j]);
    pbase[p] = i * NG + j;
    pw[p] = make_float4((1.0f - t1) * (1.0f - t2), t1 * (1.0f - t2),
                        (1.0f - t1) * t2, t1 * t2);
  }
  __syncthreads();

  float acc[4] = {0, 0, 0, 0};
  for (int p = 0; p < NP; ++p) {
    int base = pbase[p];
    float4 wv = pw[p];
#pragma unroll
    for (int k = 0; k < 4; ++k) {
      size_t r = ((size_t)base * NO + (4 * t + k)) * NP + p;
      acc[k] += wv.x * fp[r] + wv.y * fp[r + 65 * PANEL] +
                wv.z * fp[r + PANEL] + wv.w * fp[r + 66 * PANEL];
    }
  }

  const float wlm = wlm_p[0];
  const int rl = relu_p[0];
  const float4* xc4 = reinterpret_cast<const float4*>(xcol);
#pragma unroll
  for (int k = 0; k < 4; ++k) {
    const int o = 4 * t + k;
    const float4* wr = reinterpret_cast<const float4*>(W + (size_t)o * ND);
    float s = 0.0f;
#pragma unroll 8
    for (int d4 = 0; d4 < ND / 4; ++d4) {
      float4 wv = wr[d4];
      float4 xv = xc4[d4];
      s = fmaf(wv.x, xv.x, s);
      s = fmaf(wv.y, xv.y, s);
      s = fmaf(wv.z, xv.z, s);
      s = fmaf(wv.w, xv.w, s);
    }
    s += bias_l[o];
    if (rl) s = fmaxf(s, 0.0f);
    out[(size_t)o * NB + b] = s + wlm * acc[k];
  }
}

extern "C" void kernel_launch(void* const* d_in, const int* in_sizes, int n_in,
                              void* d_out, int out_size, void* d_ws, size_t ws_size,
                              hipStream_t stream) {
  const float* x     = reinterpret_cast<const float*>(d_in[0]);
  const float* wlm   = reinterpret_cast<const float*>(d_in[1]);
  const int*   relu  = reinterpret_cast<const int*>(d_in[2]);
  const float* fp    = reinterpret_cast<const float*>(d_in[3]);
  const float* scale = reinterpret_cast<const float*>(d_in[4]);
  const float* biasp = reinterpret_cast<const float*>(d_in[5]);
  const float* W     = reinterpret_cast<const float*>(d_in[6]);
  const float* bl    = reinterpret_cast<const float*>(d_in[7]);
  float* out = reinterpret_cast<float*>(d_out);

  const size_t need = (size_t)NG * NG * PANEL * sizeof(__half);  // 132 MiB
  if (ws_size >= need) {
    __half* fpt = reinterpret_cast<__half*>(d_ws);
    lmkan_transpose2<<<NG * NG, 256, 0, stream>>>(fp, fpt);
    lmkan_gather4<<<NB, 256, 0, stream>>>(x, scale, biasp, wlm, fpt, out);
    lmkan_linear<<<NB / 32, 256, 0, stream>>>(x, W, bl, relu, out);
  } else {
    lmkan_gather_direct<<<NB, 64, 0, stream>>>(x, scale, biasp, W, bl, wlm, relu, fp, out);
  }
}

// Round 4
// 193.591 us; speedup vs baseline: 1.1733x; 1.0078x over previous
//
#include <hip/hip_runtime.h>
#include <hip/hip_fp16.h>

// LMKAN_2D: out(O=256,B=4096) = relu(W(256x128)@x(128x4096) + bias_l)
//           + w_lm * sum_p bilinear4(fp[i,j,:,p])
// K1 transpose: fp[i][j][o][p] f32 -> fpt[i][p][j][o] f16 (132 MiB, L3-fit).
//    NT loads on src (read-once) so fpt stays L3-resident for the gather.
// K2 gather: block per b (256 thr = 4 waves x 16 p's). Per p: two contiguous
//    1KB wave reads (rows i, i+1; j/j+1 packed inside), depth-1 software
//    prefetch, lane-halves own j / j+1, shfl + LDS merge.
// K3 linear: separate 128-block GEMM, RMW-adds relu(Wx+b) into out.

#define NB 4096
#define ND 128
#define NO 256
#define NP 64
#define NG 65
#define PANEL 16384              // 256*64 elements per (i,j) panel
#define ROW2OFF (64 * 65 * 256)  // halves: (i,p,j,0) -> (i+1,p,j,0)

typedef float f32x4 __attribute__((ext_vector_type(4)));
union Pack8 { __half h[8]; uint4 v; };

__device__ __forceinline__ int bsearch65(const float* B, float v) {
  int lo = 0, hi = 65;
  while (lo < hi) {
    int m = (lo + hi) >> 1;
    if (B[m] <= v) lo = m + 1; else hi = m;
  }
  int i = lo - 1;
  return i < 0 ? 0 : (i > 63 ? 63 : i);
}

// ---- K1: transpose fp -> fpt[i][p][j][o] fp16 ----
__global__ __launch_bounds__(256) void lmkan_transpose2(
    const float* __restrict__ src, __half* __restrict__ dst) {
  const int panel = blockIdx.x;       // = i*65 + j
  const int i = panel / NG, j = panel % NG;
  const int t = threadIdx.x;
  __shared__ __half lds[256 * 72];    // [o][64+8 pad]

  const f32x4* s4 = reinterpret_cast<const f32x4*>(src + (size_t)panel * PANEL);
#pragma unroll
  for (int k = 0; k < 16; ++k) {
    int idx4 = t + 256 * k;           // float4 index; 1KB contiguous per wave
    f32x4 v = __builtin_nontemporal_load(&s4[idx4]);  // read-once: don't pollute L3
    int o = idx4 >> 4;
    int p0 = (idx4 & 15) * 4;
    union { __half2 h2[2]; uint2 u; } pk;
    pk.h2[0] = __floats2half2_rn(v[0], v[1]);
    pk.h2[1] = __floats2half2_rn(v[2], v[3]);
    *reinterpret_cast<uint2*>(&lds[o * 72 + p0]) = pk.u;
  }
  __syncthreads();

  const int p = t & 63, oc = t >> 6;  // thread -> (p-row, o-chunk of 64)
  __half* dbase = dst + (((size_t)(i * 64 + p) * NG + j) * NO) + oc * 64;
#pragma unroll
  for (int s = 0; s < 8; ++s) {
    Pack8 pk;
#pragma unroll
    for (int r = 0; r < 8; ++r) pk.h[r] = lds[(oc * 64 + 8 * s + r) * 72 + p];
    *reinterpret_cast<uint4*>(dbase + 8 * s) = pk.v;
  }
}

__device__ __forceinline__ void fma8(float acc[8], float w, uint4 v) {
  const __half2* h = reinterpret_cast<const __half2*>(&v);
#pragma unroll
  for (int k = 0; k < 4; ++k) {
    float2 f = __half22float2(h[k]);
    acc[2 * k]     = fmaf(w, f.x, acc[2 * k]);
    acc[2 * k + 1] = fmaf(w, f.y, acc[2 * k + 1]);
  }
}

// ---- K2: gather, out = wlm * lmkan ----
__global__ __launch_bounds__(256) void lmkan_gather4(
    const float* __restrict__ x, const float* __restrict__ scale,
    const float* __restrict__ biasp, const float* __restrict__ wlm_p,
    const __half* __restrict__ fpt, float* __restrict__ out) {
  const int b = blockIdx.x;
  const int t = threadIdx.x;   // 0..255
  const int w = t >> 6;        // wave -> p in [16w, 16w+16)
  const int l = t & 63;
  const int sideJ = l >> 5;    // 0: corner j, 1: corner j+1
  const int o0 = 8 * (l & 31); // o block [o0, o0+8)

  __shared__ float borders[66];
  __shared__ float xcol[ND];
  __shared__ int pbaseEl[NP];      // half-index of (i, p, j, 0)
  __shared__ float2 pws[2][NP];    // [side][p] = {w(row i), w(row i+1)}
  __shared__ float lm[4][NO];

  if (t < 65) {
    float pk = fminf(fmaxf((float)t * (1.0f / 64.0f), 0.0078125f), 0.9921875f);
    borders[t] = 1.41421356237309515f * erfinvf(2.0f * pk - 1.0f);
  }
  if (t < ND) xcol[t] = x[(size_t)t * NB + b];
  __syncthreads();

  if (t < NP) {
    const int p = t;
    float x1 = xcol[2 * p]     * scale[2 * p]     + biasp[2 * p];
    float x2 = xcol[2 * p + 1] * scale[2 * p + 1] + biasp[2 * p + 1];
    const float lo = borders[0];
    const float hi = borders[64] - 1e-6f;
    x1 = fminf(fmaxf(x1, lo), hi);
    x2 = fminf(fmaxf(x2, lo), hi);
    int i = bsearch65(borders, x1);
    int j = bsearch65(borders, x2);
    float t1 = (x1 - borders[i]) / (borders[i + 1] - borders[i]);
    float t2 = (x2 - borders[j]) / (borders[j + 1] - borders[j]);
    pbaseEl[p] = ((i * 64 + p) * NG + j) * NO;
    pws[0][p] = make_float2((1.0f - t1) * (1.0f - t2), t1 * (1.0f - t2)); // side j
    pws[1][p] = make_float2((1.0f - t1) * t2,          t1 * t2);          // side j+1
  }
  __syncthreads();

  float acc[8] = {0, 0, 0, 0, 0, 0, 0, 0};
  const int p0 = w * 16;
  const int loff = 8 * l;

  // depth-1 software pipeline: prefetch next p while FMAing current
  const __half* q = fpt + pbaseEl[p0] + loff;
  uint4 v0 = *reinterpret_cast<const uint4*>(q);
  uint4 v1 = *reinterpret_cast<const uint4*>(q + ROW2OFF);
#pragma unroll
  for (int pi = 0; pi < 16; ++pi) {
    const int p = p0 + pi;
    uint4 c0 = v0, c1 = v1;
    if (pi < 15) {
      const __half* qn = fpt + pbaseEl[p + 1] + loff;
      v0 = *reinterpret_cast<const uint4*>(qn);
      v1 = *reinterpret_cast<const uint4*>(qn + ROW2OFF);
    }
    const float2 wv = pws[sideJ][p];
    fma8(acc, wv.x, c0);   // row i
    fma8(acc, wv.y, c1);   // row i+1
  }
  // merge j / j+1 lane-halves
#pragma unroll
  for (int k = 0; k < 8; ++k) acc[k] += __shfl_xor(acc[k], 32, 64);
  if (l < 32) {
#pragma unroll
    for (int k = 0; k < 8; ++k) lm[w][o0 + k] = acc[k];
  }
  __syncthreads();

  const int o = t;
  float lmsum = lm[0][o] + lm[1][o] + lm[2][o] + lm[3][o];
  out[(size_t)o * NB + b] = wlm_p[0] * lmsum;
}

// ---- K3: out += relu(W@x + bias) ----
__global__ __launch_bounds__(256) void lmkan_linear(
    const float* __restrict__ x, const float* __restrict__ W,
    const float* __restrict__ bias_l, const int* __restrict__ relu_p,
    float* __restrict__ out) {
  const int b0 = blockIdx.x * 32;
  const int t = threadIdx.x;          // = output row o
  __shared__ __align__(16) float xs[32 * 132];  // [bb][d], pad 132

#pragma unroll
  for (int k = 0; k < 16; ++k) {
    int idx = t + 256 * k;            // idx = d*32 + bb -> coalesced in b
    int d = idx >> 5, bb = idx & 31;
    xs[bb * 132 + d] = x[(size_t)d * NB + b0 + bb];
  }
  __syncthreads();

  float acc[32];
#pragma unroll
  for (int bb = 0; bb < 32; ++bb) acc[bb] = 0.0f;

  const float4* W4 = reinterpret_cast<const float4*>(W + (size_t)t * ND);
#pragma unroll 8
  for (int d4 = 0; d4 < 32; ++d4) {
    float4 wv = W4[d4];
#pragma unroll
    for (int bb = 0; bb < 32; ++bb) {
      float4 xv = *reinterpret_cast<const float4*>(&xs[bb * 132 + d4 * 4]);
      acc[bb] = fmaf(wv.x, xv.x, acc[bb]);
      acc[bb] = fmaf(wv.y, xv.y, acc[bb]);
      acc[bb] = fmaf(wv.z, xv.z, acc[bb]);
      acc[bb] = fmaf(wv.w, xv.w, acc[bb]);
    }
  }

  const float bias = bias_l[t];
  const int rl = relu_p[0];
  float* orow = out + (size_t)t * NB + b0;
#pragma unroll
  for (int bb = 0; bb < 32; ++bb) {
    float v = acc[bb] + bias;
    if (rl) v = fmaxf(v, 0.0f);
    orow[bb] += v;   // RMW: gather already wrote wlm*lmkan
  }
}

// ---- Fallback: direct fp32 gather, fused linear (exact, slow) ----
__global__ __launch_bounds__(64) void lmkan_gather_direct(
    const float* __restrict__ x, const float* __restrict__ scale,
    const float* __restrict__ biasp, const float* __restrict__ W,
    const float* __restrict__ bias_l, const float* __restrict__ wlm_p,
    const int* __restrict__ relu_p, const float* __restrict__ fp,
    float* __restrict__ out) {
  const int b = blockIdx.x;
  const int t = threadIdx.x;

  __shared__ float borders[66];
  __shared__ __align__(16) float xcol[ND];
  __shared__ int pbase[NP];
  __shared__ float4 pw[NP];

  for (int k = t; k < 65; k += 64) {
    float pk = fminf(fmaxf((float)k * (1.0f / 64.0f), 0.0078125f), 0.9921875f);
    borders[k] = 1.41421356237309515f * erfinvf(2.0f * pk - 1.0f);
  }
  xcol[t]      = x[(size_t)t * NB + b];
  xcol[t + 64] = x[(size_t)(t + 64) * NB + b];
  __syncthreads();

  {
    const int p = t;
    float x1 = xcol[2 * p]     * scale[2 * p]     + biasp[2 * p];
    float x2 = xcol[2 * p + 1] * scale[2 * p + 1] + biasp[2 * p + 1];
    const float lo = borders[0];
    const float hi = borders[64] - 1e-6f;
    x1 = fminf(fmaxf(x1, lo), hi);
    x2 = fminf(fmaxf(x2, lo), hi);
    int i = bsearch65(borders, x1);
    int j = bsearch65(borders, x2);
    float t1 = (x1 - borders[i]) / (borders[i + 1] - borders[i]);
    float t2 = (x2 - borders[j]) / (borders[j + 1] - borders[j]);
    pbase[p] = i * NG + j;
    pw[p] = make_float4((1.0f - t1) * (1.0f - t2), t1 * (1.0f - t2),
                        (1.0f - t1) * t2, t1 * t2);
  }
  __syncthreads();

  float acc[4] = {0, 0, 0, 0};
  for (int p = 0; p < NP; ++p) {
    int base = pbase[p];
    float4 wv = pw[p];
#pragma unroll
    for (int k = 0; k < 4; ++k) {
      size_t r = ((size_t)base * NO + (4 * t + k)) * NP + p;
      acc[k] += wv.x * fp[r] + wv.y * fp[r + 65 * PANEL] +
                wv.z * fp[r + PANEL] + wv.w * fp[r + 66 * PANEL];
    }
  }

  const float wlm = wlm_p[0];
  const int rl = relu_p[0];
  const float4* xc4 = reinterpret_cast<const float4*>(xcol);
#pragma unroll
  for (int k = 0; k < 4; ++k) {
    const int o = 4 * t + k;
    const float4* wr = reinterpret_cast<const float4*>(W + (size_t)o * ND);
    float s = 0.0f;
#pragma unroll 8
    for (int d4 = 0; d4 < ND / 4; ++d4) {
      float4 wv = wr[d4];
      float4 xv = xc4[d4];
      s = fmaf(wv.x, xv.x, s);
      s = fmaf(wv.y, xv.y, s);
      s = fmaf(wv.z, xv.z, s);
      s = fmaf(wv.w, xv.w, s);
    }
    s += bias_l[o];
    if (rl) s = fmaxf(s, 0.0f);
    out[(size_t)o * NB + b] = s + wlm * acc[k];
  }
}

extern "C" void kernel_launch(void* const* d_in, const int* in_sizes, int n_in,
                              void* d_out, int out_size, void* d_ws, size_t ws_size,
                              hipStream_t stream) {
  const float* x     = reinterpret_cast<const float*>(d_in[0]);
  const float* wlm   = reinterpret_cast<const float*>(d_in[1]);
  const int*   relu  = reinterpret_cast<const int*>(d_in[2]);
  const float* fp    = reinterpret_cast<const float*>(d_in[3]);
  const float* scale = reinterpret_cast<const float*>(d_in[4]);
  const float* biasp = reinterpret_cast<const float*>(d_in[5]);
  const float* W     = reinterpret_cast<const float*>(d_in[6]);
  const float* bl    = reinterpret_cast<const float*>(d_in[7]);
  float* out = reinterpret_cast<float*>(d_out);

  const size_t need = (size_t)NG * NG * PANEL * sizeof(__half);  // 132 MiB
  if (ws_size >= need) {
    __half* fpt = reinterpret_cast<__half*>(d_ws);
    lmkan_transpose2<<<NG * NG, 256, 0, stream>>>(fp, fpt);
    lmkan_gather4<<<NB, 256, 0, stream>>>(x, scale, biasp, wlm, fpt, out);
    lmkan_linear<<<NB / 32, 256, 0, stream>>>(x, W, bl, relu, out);
  } else {
    lmkan_gather_direct<<<NB, 64, 0, stream>>>(x, scale, biasp, W, bl, wlm, relu, fp, out);
  }
}

// Round 5
// 182.404 us; speedup vs baseline: 1.2453x; 1.0613x over previous
//
#include <hip/hip_runtime.h>
#include <hip/hip_fp16.h>

// LMKAN_2D: out(O=256,B=4096) = relu(W(256x128)@x(128x4096) + bias_l)
//           + w_lm * sum_p bilinear4(fp[i,j,:,p])
// K1 transpose: fp[i][j][o][p] f32 -> fpt[panel][p][o] f16 (132 MiB, L3-fit).
//    BOTH global sides 1KB/wave contiguous (R3's stores scattered 64 lines/instr
//    because j sat between p and o). LDS XOR-swizzled: ~4-way wr / ~2-way rd.
// K2 gather: block per b (256 thr = 4 waves x 16 p's). Per p: 4 x 512B
//    coalesced wave-reads (corners), lane owns o=4l..4l+3, depth-1 prefetch,
//    LDS merge of 4 waves. No shfl needed.
// K3 linear: separate 128-block GEMM, RMW-adds relu(Wx+b) into out.

#define NB 4096
#define ND 128
#define NO 256
#define NP 64
#define NG 65
#define PANEL 16384  // 256*64 elements per (i,j) panel

typedef float f32x4 __attribute__((ext_vector_type(4)));
union Pack8 { __half h[8]; uint4 v; };

__device__ __forceinline__ int bsearch65(const float* B, float v) {
  int lo = 0, hi = 65;
  while (lo < hi) {
    int m = (lo + hi) >> 1;
    if (B[m] <= v) lo = m + 1; else hi = m;
  }
  int i = lo - 1;
  return i < 0 ? 0 : (i > 63 ? 63 : i);
}

// ---- K1: transpose fp[panel][o][p] f32 -> fpt[panel][p][o] f16 ----
__global__ __launch_bounds__(256) void lmkan_transpose3(
    const float* __restrict__ src, __half* __restrict__ dst) {
  const int panel = blockIdx.x;
  const int t = threadIdx.x;
  __shared__ __half lds[256 * 72];   // [o][72], p XOR-swizzled inside row

  const f32x4* s4 = reinterpret_cast<const f32x4*>(src + (size_t)panel * PANEL);
#pragma unroll
  for (int k = 0; k < 16; ++k) {
    int idx4 = t + 256 * k;          // 1KB contiguous per wave
    f32x4 v = __builtin_nontemporal_load(&s4[idx4]);  // read-once: skip L3
    int o = idx4 >> 4;
    int p0 = (idx4 & 15) * 4;
    int p0s = p0 ^ (((o >> 3) & 15) << 2);   // keeps 4-half blocks intact
    union { __half2 h2[2]; uint2 u; } pk;
    pk.h2[0] = __floats2half2_rn(v[0], v[1]);
    pk.h2[1] = __floats2half2_rn(v[2], v[3]);
    *reinterpret_cast<uint2*>(&lds[o * 72 + p0s]) = pk.u;
  }
  __syncthreads();

  const int l = t & 63, w = t >> 6;
  const int o0 = (l & 31) * 8;       // lane's o-chunk
  const int swz = (l & 15) << 2;     // = ((o0+r)>>3 & 15)<<2, const over r
#pragma unroll
  for (int ss = 0; ss < 8; ++ss) {
    int p = ss * 8 + w * 2 + (l >> 5);
    int prow = ((p & ~3) ^ swz) + (p & 3);
    Pack8 pk;
#pragma unroll
    for (int r = 0; r < 8; ++r) pk.h[r] = lds[(o0 + r) * 72 + prow];
    // lanes 0..31 -> row p (512B), lanes 32..63 -> row p+1: 1KB contiguous
    *reinterpret_cast<uint4*>(dst + ((size_t)panel * 64 + p) * NO + o0) = pk.v;
  }
}

__device__ __forceinline__ void fma4h(float acc[4], float w, uint2 v) {
  __half2 h0 = *reinterpret_cast<__half2*>(&v.x);
  __half2 h1 = *reinterpret_cast<__half2*>(&v.y);
  float2 f0 = __half22float2(h0);
  float2 f1 = __half22float2(h1);
  acc[0] = fmaf(w, f0.x, acc[0]);
  acc[1] = fmaf(w, f0.y, acc[1]);
  acc[2] = fmaf(w, f1.x, acc[2]);
  acc[3] = fmaf(w, f1.y, acc[3]);
}

// ---- K2: gather, out = wlm * lmkan ----
__global__ __launch_bounds__(256) void lmkan_gather5(
    const float* __restrict__ x, const float* __restrict__ scale,
    const float* __restrict__ biasp, const float* __restrict__ wlm_p,
    const __half* __restrict__ fpt, float* __restrict__ out) {
  const int b = blockIdx.x;
  const int t = threadIdx.x;   // 0..255
  const int w = t >> 6;        // wave -> p in [16w, 16w+16)
  const int l = t & 63;        // lane owns o = 4l..4l+3

  __shared__ float borders[66];
  __shared__ float xcol[ND];
  __shared__ int pbaseEl[NP];        // element index of (panel(i,j), p, o=0)
  __shared__ float4 pw[NP];          // {w00, w01(j+1), w10(i+1), w11}
  __shared__ __align__(16) float lm[4][NO];

  if (t < 65) {
    float pk = fminf(fmaxf((float)t * (1.0f / 64.0f), 0.0078125f), 0.9921875f);
    borders[t] = 1.41421356237309515f * erfinvf(2.0f * pk - 1.0f);
  }
  if (t < ND) xcol[t] = x[(size_t)t * NB + b];
  __syncthreads();

  if (t < NP) {
    const int p = t;
    float x1 = xcol[2 * p]     * scale[2 * p]     + biasp[2 * p];
    float x2 = xcol[2 * p + 1] * scale[2 * p + 1] + biasp[2 * p + 1];
    const float lo = borders[0];
    const float hi = borders[64] - 1e-6f;
    x1 = fminf(fmaxf(x1, lo), hi);
    x2 = fminf(fmaxf(x2, lo), hi);
    int i = bsearch65(borders, x1);
    int j = bsearch65(borders, x2);
    float t1 = (x1 - borders[i]) / (borders[i + 1] - borders[i]);
    float t2 = (x2 - borders[j]) / (borders[j + 1] - borders[j]);
    pbaseEl[p] = ((i * NG + j) * 64 + p) * NO;
    pw[p] = make_float4((1.0f - t1) * (1.0f - t2),  // (i,   j)
                        (1.0f - t1) * t2,           // (i,   j+1): +PANEL
                        t1 * (1.0f - t2),           // (i+1, j)  : +65*PANEL
                        t1 * t2);                   // (i+1, j+1): +66*PANEL
  }
  __syncthreads();

  float acc[4] = {0, 0, 0, 0};
  const int p0 = w * 16;
  const int loff = 4 * l;

  // depth-1 software pipeline
  const __half* q = fpt + pbaseEl[p0] + loff;
  uint2 vA = *reinterpret_cast<const uint2*>(q);
  uint2 vB = *reinterpret_cast<const uint2*>(q + PANEL);
  uint2 vC = *reinterpret_cast<const uint2*>(q + 65 * PANEL);
  uint2 vD = *reinterpret_cast<const uint2*>(q + 66 * PANEL);
#pragma unroll
  for (int pi = 0; pi < 16; ++pi) {
    const int p = p0 + pi;
    uint2 cA = vA, cB = vB, cC = vC, cD = vD;
    if (pi < 15) {
      const __half* qn = fpt + pbaseEl[p + 1] + loff;
      vA = *reinterpret_cast<const uint2*>(qn);
      vB = *reinterpret_cast<const uint2*>(qn + PANEL);
      vC = *reinterpret_cast<const uint2*>(qn + 65 * PANEL);
      vD = *reinterpret_cast<const uint2*>(qn + 66 * PANEL);
    }
    const float4 wv = pw[p];
    fma4h(acc, wv.x, cA);
    fma4h(acc, wv.y, cB);
    fma4h(acc, wv.z, cC);
    fma4h(acc, wv.w, cD);
  }
  *reinterpret_cast<float4*>(&lm[w][loff]) =
      make_float4(acc[0], acc[1], acc[2], acc[3]);
  __syncthreads();

  const int o = t;
  float lmsum = lm[0][o] + lm[1][o] + lm[2][o] + lm[3][o];
  out[(size_t)o * NB + b] = wlm_p[0] * lmsum;
}

// ---- K3: out += relu(W@x + bias) ----
__global__ __launch_bounds__(256) void lmkan_linear(
    const float* __restrict__ x, const float* __restrict__ W,
    const float* __restrict__ bias_l, const int* __restrict__ relu_p,
    float* __restrict__ out) {
  const int b0 = blockIdx.x * 32;
  const int t = threadIdx.x;          // = output row o
  __shared__ __align__(16) float xs[32 * 132];  // [bb][d], pad 132

#pragma unroll
  for (int k = 0; k < 16; ++k) {
    int idx = t + 256 * k;            // idx = d*32 + bb -> coalesced in b
    int d = idx >> 5, bb = idx & 31;
    xs[bb * 132 + d] = x[(size_t)d * NB + b0 + bb];
  }
  __syncthreads();

  float acc[32];
#pragma unroll
  for (int bb = 0; bb < 32; ++bb) acc[bb] = 0.0f;

  const float4* W4 = reinterpret_cast<const float4*>(W + (size_t)t * ND);
#pragma unroll 8
  for (int d4 = 0; d4 < 32; ++d4) {
    float4 wv = W4[d4];
#pragma unroll
    for (int bb = 0; bb < 32; ++bb) {
      float4 xv = *reinterpret_cast<const float4*>(&xs[bb * 132 + d4 * 4]);
      acc[bb] = fmaf(wv.x, xv.x, acc[bb]);
      acc[bb] = fmaf(wv.y, xv.y, acc[bb]);
      acc[bb] = fmaf(wv.z, xv.z, acc[bb]);
      acc[bb] = fmaf(wv.w, xv.w, acc[bb]);
    }
  }

  const float bias = bias_l[t];
  const int rl = relu_p[0];
  float* orow = out + (size_t)t * NB + b0;
#pragma unroll
  for (int bb = 0; bb < 32; ++bb) {
    float v = acc[bb] + bias;
    if (rl) v = fmaxf(v, 0.0f);
    orow[bb] += v;   // RMW: gather already wrote wlm*lmkan
  }
}

// ---- Fallback: direct fp32 gather, fused linear (exact, slow) ----
__global__ __launch_bounds__(64) void lmkan_gather_direct(
    const float* __restrict__ x, const float* __restrict__ scale,
    const float* __restrict__ biasp, const float* __restrict__ W,
    const float* __restrict__ bias_l, const float* __restrict__ wlm_p,
    const int* __restrict__ relu_p, const float* __restrict__ fp,
    float* __restrict__ out) {
  const int b = blockIdx.x;
  const int t = threadIdx.x;

  __shared__ float borders[66];
  __shared__ __align__(16) float xcol[ND];
  __shared__ int pbase[NP];
  __shared__ float4 pw[NP];

  for (int k = t; k < 65; k += 64) {
    float pk = fminf(fmaxf((float)k * (1.0f / 64.0f), 0.0078125f), 0.9921875f);
    borders[k] = 1.41421356237309515f * erfinvf(2.0f * pk - 1.0f);
  }
  xcol[t]      = x[(size_t)t * NB + b];
  xcol[t + 64] = x[(size_t)(t + 64) * NB + b];
  __syncthreads();

  {
    const int p = t;
    float x1 = xcol[2 * p]     * scale[2 * p]     + biasp[2 * p];
    float x2 = xcol[2 * p + 1] * scale[2 * p + 1] + biasp[2 * p + 1];
    const float lo = borders[0];
    const float hi = borders[64] - 1e-6f;
    x1 = fminf(fmaxf(x1, lo), hi);
    x2 = fminf(fmaxf(x2, lo), hi);
    int i = bsearch65(borders, x1);
    int j = bsearch65(borders, x2);
    float t1 = (x1 - borders[i]) / (borders[i + 1] - borders[i]);
    float t2 = (x2 - borders[j]) / (borders[j + 1] - borders[j]);
    pbase[p] = i * NG + j;
    pw[p] = make_float4((1.0f - t1) * (1.0f - t2), t1 * (1.0f - t2),
                        (1.0f - t1) * t2, t1 * t2);
  }
  __syncthreads();

  float acc[4] = {0, 0, 0, 0};
  for (int p = 0; p < NP; ++p) {
    int base = pbase[p];
    float4 wv = pw[p];
#pragma unroll
    for (int k = 0; k < 4; ++k) {
      size_t r = ((size_t)base * NO + (4 * t + k)) * NP + p;
      acc[k] += wv.x * fp[r] + wv.y * fp[r + 65 * PANEL] +
                wv.z * fp[r + PANEL] + wv.w * fp[r + 66 * PANEL];
    }
  }

  const float wlm = wlm_p[0];
  const int rl = relu_p[0];
  const float4* xc4 = reinterpret_cast<const float4*>(xcol);
#pragma unroll
  for (int k = 0; k < 4; ++k) {
    const int o = 4 * t + k;
    const float4* wr = reinterpret_cast<const float4*>(W + (size_t)o * ND);
    float s = 0.0f;
#pragma unroll 8
    for (int d4 = 0; d4 < ND / 4; ++d4) {
      float4 wv = wr[d4];
      float4 xv = xc4[d4];
      s = fmaf(wv.x, xv.x, s);
      s = fmaf(wv.y, xv.y, s);
      s = fmaf(wv.z, xv.z, s);
      s = fmaf(wv.w, xv.w, s);
    }
    s += bias_l[o];
    if (rl) s = fmaxf(s, 0.0f);
    out[(size_t)o * NB + b] = s + wlm * acc[k];
  }
}

extern "C" void kernel_launch(void* const* d_in, const int* in_sizes, int n_in,
                              void* d_out, int out_size, void* d_ws, size_t ws_size,
                              hipStream_t stream) {
  const float* x     = reinterpret_cast<const float*>(d_in[0]);
  const float* wlm   = reinterpret_cast<const float*>(d_in[1]);
  const int*   relu  = reinterpret_cast<const int*>(d_in[2]);
  const float* fp    = reinterpret_cast<const float*>(d_in[3]);
  const float* scale = reinterpret_cast<const float*>(d_in[4]);
  const float* biasp = reinterpret_cast<const float*>(d_in[5]);
  const float* W     = reinterpret_cast<const float*>(d_in[6]);
  const float* bl    = reinterpret_cast<const float*>(d_in[7]);
  float* out = reinterpret_cast<float*>(d_out);

  const size_t need = (size_t)NG * NG * PANEL * sizeof(__half);  // 132 MiB
  if (ws_size >= need) {
    __half* fpt = reinterpret_cast<__half*>(d_ws);
    lmkan_transpose3<<<NG * NG, 256, 0, stream>>>(fp, fpt);
    lmkan_gather5<<<NB, 256, 0, stream>>>(x, scale, biasp, wlm, fpt, out);
    lmkan_linear<<<NB / 32, 256, 0, stream>>>(x, W, bl, relu, out);
  } else {
    lmkan_gather_direct<<<NB, 64, 0, stream>>>(x, scale, biasp, W, bl, wlm, relu, fp, out);
  }
}